// Round 2
// baseline (158.796 us; speedup 1.0000x reference)
//
#include <hip/hip_runtime.h>
#include <stdint.h>

#define NN 8192
#define FIN 512
#define FOUT 64
#define ALPHA 0.2f

typedef float f32x4 __attribute__((ext_vector_type(4)));
typedef int   i32x4 __attribute__((ext_vector_type(4)));
typedef short bf16x8 __attribute__((ext_vector_type(8)));

__device__ __forceinline__ unsigned short f2bf(float f) {
  union { float f; unsigned u; } v; v.f = f;
  unsigned r = (v.u + 0x7fffu + ((v.u >> 16) & 1u)) >> 16;
  return (unsigned short)r;
}

// ---------------- Phase 1: h = x@W (fp32), f1 = h@a1, f2 = h@a2, ht = bf16(h)^T -------------
__global__ __launch_bounds__(256) void prep_kernel(
    const float* __restrict__ x, const float* __restrict__ W,
    const float* __restrict__ a, unsigned short* __restrict__ ht,
    float* __restrict__ f1, float* __restrict__ f2) {
  const int lane = threadIdx.x & 63;
  const int g = blockIdx.x * 4 + (threadIdx.x >> 6);  // wave id 0..1023
  const int i0 = g * 8;

  float acc[8];
#pragma unroll
  for (int r = 0; r < 8; ++r) acc[r] = 0.0f;

  for (int k = 0; k < FIN; k += 4) {
    float w0 = W[(k + 0) * FOUT + lane];
    float w1 = W[(k + 1) * FOUT + lane];
    float w2 = W[(k + 2) * FOUT + lane];
    float w3 = W[(k + 3) * FOUT + lane];
#pragma unroll
    for (int r = 0; r < 8; ++r) {
      f32x4 xv = *(const f32x4*)(x + (size_t)(i0 + r) * FIN + k);
      acc[r] = fmaf(xv[0], w0, acc[r]);
      acc[r] = fmaf(xv[1], w1, acc[r]);
      acc[r] = fmaf(xv[2], w2, acc[r]);
      acc[r] = fmaf(xv[3], w3, acc[r]);
    }
  }

  const float a1c = a[lane];
  const float a2c = a[FOUT + lane];
#pragma unroll
  for (int r = 0; r < 8; ++r) {
    float p1 = acc[r] * a1c;
    float p2 = acc[r] * a2c;
#pragma unroll
    for (int off = 32; off >= 1; off >>= 1) {
      p1 += __shfl_xor(p1, off, 64);
      p2 += __shfl_xor(p2, off, 64);
    }
    if (lane == 0) { f1[i0 + r] = p1; f2[i0 + r] = p2; }
  }

  unsigned short hs[8];
#pragma unroll
  for (int r = 0; r < 8; ++r) hs[r] = f2bf(acc[r]);
  *(uint4*)(ht + (size_t)lane * NN + i0) = *(uint4*)hs;
}

// ---------------- Phase 2: fused mask + unnormalized softmax + PV (MFMA) + elu -------------
// One block (16 waves) per 16 output rows. Wave wv handles j in [wv*512, (wv+1)*512).
__global__ __launch_bounds__(1024, 8) void attn_kernel(
    const int* __restrict__ adj, const unsigned short* __restrict__ ht,
    const float* __restrict__ f1, const float* __restrict__ f2,
    float* __restrict__ out) {
  __shared__ float lds_num[16][16][64];   // 64 KB
  __shared__ float lds_den[16][16];       // 1 KB

  const int tid = threadIdx.x;
  const int lane = tid & 63;
  const int wv = tid >> 6;     // 0..15
  const int rg = blockIdx.x;   // 0..511
  const int r15 = lane & 15;
  const int kgrp = lane >> 4;  // 0..3
  const int row = rg * 16 + r15;

  const float f1v = f1[row];
  const int* adjrow = adj + (size_t)row * NN;
  const int jbase = wv * 512 + kgrp * 8;

  f32x4 acc0 = {0.f, 0.f, 0.f, 0.f};
  f32x4 acc1 = acc0, acc2 = acc0, acc3 = acc0;
  float den = 0.0f;

  // depth-2 adj pipeline (HBM stream), depth-1 f2 (L2-resident)
  i32x4 a0A = *(const i32x4*)(adjrow + jbase);
  i32x4 a0B = *(const i32x4*)(adjrow + jbase + 4);
  i32x4 a1A = *(const i32x4*)(adjrow + jbase + 32);
  i32x4 a1B = *(const i32x4*)(adjrow + jbase + 36);
  f32x4 fA = *(const f32x4*)(f2 + jbase);
  f32x4 fB = *(const f32x4*)(f2 + jbase + 4);

  for (int t = 0; t < 16; ++t) {
    const int jl = jbase + t * 32;
    const int j2 = jbase + ((t + 2) & 15) * 32;   // depth-2 (wraps: dummy reload)
    const int j1 = jbase + ((t + 1) & 15) * 32;

    i32x4 naA = *(const i32x4*)(adjrow + j2);
    i32x4 naB = *(const i32x4*)(adjrow + j2 + 4);
    f32x4 nfA = *(const f32x4*)(f2 + j1);
    f32x4 nfB = *(const f32x4*)(f2 + j1 + 4);

    bf16x8 b0 = *(const bf16x8*)(ht + (size_t)(0 * 16 + r15) * NN + jl);
    bf16x8 b1 = *(const bf16x8*)(ht + (size_t)(1 * 16 + r15) * NN + jl);
    bf16x8 b2 = *(const bf16x8*)(ht + (size_t)(2 * 16 + r15) * NN + jl);
    bf16x8 b3 = *(const bf16x8*)(ht + (size_t)(3 * 16 + r15) * NN + jl);

    float w[8];
#pragma unroll
    for (int e = 0; e < 4; ++e) {
      float s = f1v + fA[e];
      float l = fmaxf(s, ALPHA * s);
      float ev = __expf(l);
      w[e] = (a0A[e] > 0) ? ev : 0.0f;
    }
#pragma unroll
    for (int e = 0; e < 4; ++e) {
      float s = f1v + fB[e];
      float l = fmaxf(s, ALPHA * s);
      float ev = __expf(l);
      w[4 + e] = (a0B[e] > 0) ? ev : 0.0f;
    }
    den += ((w[0] + w[1]) + (w[2] + w[3])) + ((w[4] + w[5]) + (w[6] + w[7]));

    union { unsigned short us[8]; bf16x8 v; } pk;
#pragma unroll
    for (int e = 0; e < 8; ++e) pk.us[e] = f2bf(w[e]);

    acc0 = __builtin_amdgcn_mfma_f32_16x16x32_bf16(pk.v, b0, acc0, 0, 0, 0);
    acc1 = __builtin_amdgcn_mfma_f32_16x16x32_bf16(pk.v, b1, acc1, 0, 0, 0);
    acc2 = __builtin_amdgcn_mfma_f32_16x16x32_bf16(pk.v, b2, acc2, 0, 0, 0);
    acc3 = __builtin_amdgcn_mfma_f32_16x16x32_bf16(pk.v, b3, acc3, 0, 0, 0);

    a0A = a1A; a0B = a1B; a1A = naA; a1B = naB;
    fA = nfA; fB = nfB;
  }

  // denominator for row r15 within this wave's j-range
  den += __shfl_xor(den, 16, 64);
  den += __shfl_xor(den, 32, 64);

  // C layout of 16x16x32 MFMA: col = lane&15, row = (lane>>4)*4 + reg
#pragma unroll
  for (int r = 0; r < 4; ++r) {
    lds_num[wv][kgrp * 4 + r][0 * 16 + r15] = acc0[r];
    lds_num[wv][kgrp * 4 + r][1 * 16 + r15] = acc1[r];
    lds_num[wv][kgrp * 4 + r][2 * 16 + r15] = acc2[r];
    lds_num[wv][kgrp * 4 + r][3 * 16 + r15] = acc3[r];
  }
  if (lane < 16) lds_den[wv][lane] = den;
  __syncthreads();

  // combine 16 waves, divide, elu, store: one element per thread
  {
    const int orow = tid >> 6;
    const int ocol = tid & 63;
    float s = 0.0f, d = 0.0f;
#pragma unroll
    for (int w2 = 0; w2 < 16; ++w2) {
      s += lds_num[w2][orow][ocol];
      d += lds_den[w2][orow];
    }
    float v = s / d;
    out[(size_t)(rg * 16 + orow) * FOUT + ocol] = (v > 0.0f) ? v : (__expf(v) - 1.0f);
  }
}

extern "C" void kernel_launch(void* const* d_in, const int* in_sizes, int n_in,
                              void* d_out, int out_size, void* d_ws, size_t ws_size,
                              hipStream_t stream) {
  const float* x = (const float*)d_in[0];
  const int* adj = (const int*)d_in[1];
  const float* W = (const float*)d_in[2];
  const float* a = (const float*)d_in[3];
  float* out = (float*)d_out;

  char* ws = (char*)d_ws;
  unsigned short* ht = (unsigned short*)ws;                    // 64*8192*2 = 1 MB
  float* f1 = (float*)(ws + (size_t)FOUT * NN * 2);            // 32 KB
  float* f2 = f1 + NN;                                         // 32 KB

  hipLaunchKernelGGL(prep_kernel, dim3(256), dim3(256), 0, stream, x, W, a, ht, f1, f2);
  hipLaunchKernelGGL(attn_kernel, dim3(512), dim3(1024), 0, stream, adj, ht, f1, f2, out);
}

// Round 3
// 127.715 us; speedup vs baseline: 1.2434x; 1.2434x over previous
//
#include <hip/hip_runtime.h>
#include <stdint.h>

#define NN 8192
#define FIN 512
#define FOUT 64
#define ALPHA 0.2f
#define TJ 512
#define NT (NN / TJ)   // 16 tiles

typedef float f32x4 __attribute__((ext_vector_type(4)));
typedef int   i32x4 __attribute__((ext_vector_type(4)));
typedef short bf16x8 __attribute__((ext_vector_type(8)));

__device__ __forceinline__ unsigned short f2bf(float f) {
  union { float f; unsigned u; } v; v.f = f;
  unsigned r = (v.u + 0x7fffu + ((v.u >> 16) & 1u)) >> 16;
  return (unsigned short)r;
}

// ---------------- Phase 1: h = x@W (fp32), f1 = h@a1, f2 = h@a2, bpack = B-fragment layout ---
// bpack[jb][cb][lane=kgrp*16+r15][e] shorts: h[j = jb*32 + kgrp*8 + e][c = cb*16 + r15]
__global__ __launch_bounds__(256) void prep_kernel(
    const float* __restrict__ x, const float* __restrict__ W,
    const float* __restrict__ a, unsigned short* __restrict__ bpack,
    float* __restrict__ f1, float* __restrict__ f2) {
  const int lane = threadIdx.x & 63;
  const int g = blockIdx.x * 4 + (threadIdx.x >> 6);  // wave id 0..1023
  const int i0 = g * 8;

  float acc[8];
#pragma unroll
  for (int r = 0; r < 8; ++r) acc[r] = 0.0f;

  for (int k = 0; k < FIN; k += 4) {
    float w0 = W[(k + 0) * FOUT + lane];
    float w1 = W[(k + 1) * FOUT + lane];
    float w2 = W[(k + 2) * FOUT + lane];
    float w3 = W[(k + 3) * FOUT + lane];
#pragma unroll
    for (int r = 0; r < 8; ++r) {
      f32x4 xv = *(const f32x4*)(x + (size_t)(i0 + r) * FIN + k);
      acc[r] = fmaf(xv[0], w0, acc[r]);
      acc[r] = fmaf(xv[1], w1, acc[r]);
      acc[r] = fmaf(xv[2], w2, acc[r]);
      acc[r] = fmaf(xv[3], w3, acc[r]);
    }
  }

  const float a1c = a[lane];
  const float a2c = a[FOUT + lane];
#pragma unroll
  for (int r = 0; r < 8; ++r) {
    float p1 = acc[r] * a1c;
    float p2 = acc[r] * a2c;
#pragma unroll
    for (int off = 32; off >= 1; off >>= 1) {
      p1 += __shfl_xor(p1, off, 64);
      p2 += __shfl_xor(p2, off, 64);
    }
    if (lane == 0) { f1[i0 + r] = p1; f2[i0 + r] = p2; }
  }

  // write B-fragment layout: e index = r (i0 multiple of 8)
  unsigned short hs[8];
#pragma unroll
  for (int r = 0; r < 8; ++r) hs[r] = f2bf(acc[r]);
  const int jb = i0 >> 5;
  const int kg = (i0 >> 3) & 3;
  const int cb = lane >> 4;
  const int rr = lane & 15;
  *(uint4*)(bpack + ((size_t)jb * 2048 + cb * 512 + kg * 128 + rr * 8)) = *(uint4*)hs;
}

// ---------------- Phase 2: contiguous-stream fused GAT attention ---------------------------
// Block = 16 rows, 16 waves. Wave w streams adj row w contiguously; weights staged via
// XOR-swizzled LDS (double-buffered); MFMA waves split K; B from bpack (contiguous 1KB loads).
__global__ __launch_bounds__(1024, 8) void attn_kernel(
    const int* __restrict__ adj, const unsigned short* __restrict__ bpack,
    const float* __restrict__ f1, const float* __restrict__ f2,
    float* __restrict__ out) {
  __shared__ __align__(16) char lds[16 * 16 * 64 * 4];  // 64 KB: pw dbuf (2x16KB) / num union
  __shared__ float lds_den[16];

  char* pwb0 = lds;            // pw buffer 0: [16 rows][512] bf16, swizzled
  char* pwb1 = lds + 16384;    // pw buffer 1
  float (*lds_num)[16][64] = (float (*)[16][64])lds;

  const int tid = threadIdx.x;
  const int lane = tid & 63;
  const int wv = tid >> 6;     // 0..15 : row owner AND k-slice owner
  const int rg = blockIdx.x;   // 0..511
  const int r15 = lane & 15;
  const int kgrp = lane >> 4;

  const int row_w = rg * 16 + wv;
  const float f1w = f1[row_w];
  const int* adjw = adj + (size_t)row_w * NN;

  // LDS addresses (bytes)
  int ard = r15 * 1024 + wv * 64 + kgrp * 16;
  ard ^= (r15 & 7) << 4;                       // swizzled A-frag read
  int awr = wv * 1024 + lane * 8;
  awr ^= (wv & 7) << 4;                        // swizzled weight write (chunk j = lane*4)

  f32x4 acc0 = {0.f, 0.f, 0.f, 0.f};
  f32x4 acc1 = acc0, acc2 = acc0, acc3 = acc0;
  float den = 0.0f;

  // prefetch adj tile 0: lane covers j = lane*4..+4 and 256+lane*4..+4 (contiguous 1KB insts)
  i32x4 a0 = *(const i32x4*)(adjw + lane * 4);
  i32x4 a1 = *(const i32x4*)(adjw + 256 + lane * 4);

  for (int t = 0; t < NT; ++t) {
    const int j0 = t * TJ;
    f32x4 fA = *(const f32x4*)(f2 + j0 + lane * 4);
    f32x4 fB = *(const f32x4*)(f2 + j0 + 256 + lane * 4);

    unsigned short ws[8];
    float dsum = 0.0f;
#pragma unroll
    for (int e = 0; e < 4; ++e) {
      float s = f1w + fA[e];
      float l = fmaxf(s, ALPHA * s);
      float ev = __expf(l);
      float wv_ = (a0[e] > 0) ? ev : 0.0f;
      dsum += wv_;
      ws[e] = f2bf(wv_);
    }
#pragma unroll
    for (int e = 0; e < 4; ++e) {
      float s = f1w + fB[e];
      float l = fmaxf(s, ALPHA * s);
      float ev = __expf(l);
      float wv_ = (a1[e] > 0) ? ev : 0.0f;
      dsum += wv_;
      ws[4 + e] = f2bf(wv_);
    }
    den += dsum;

    char* pwb = (t & 1) ? pwb1 : pwb0;
    *(uint2*)(pwb + awr) = *(uint2*)&ws[0];          // j = lane*4..+4
    *(uint2*)(pwb + awr + 512) = *(uint2*)&ws[4];    // j = 256+lane*4..+4

    __syncthreads();   // pw[t&1] visible; prior reads of pw[(t)&1] (from t-2) are 2 barriers old

    // prefetch next adj tile (in flight across MFMA phase)
    const int jn = ((t + 1) & (NT - 1)) * TJ;
    a0 = *(const i32x4*)(adjw + jn + lane * 4);
    a1 = *(const i32x4*)(adjw + jn + 256 + lane * 4);

    // MFMA phase: this wave handles k-slice [j0 + wv*32, +32)
    bf16x8 afrag = *(bf16x8*)(pwb + ard);
    const unsigned short* bp = bpack + ((size_t)(t * 16 + wv) * 2048 + lane * 8);
    bf16x8 b0 = *(const bf16x8*)(bp);
    bf16x8 b1 = *(const bf16x8*)(bp + 512);
    bf16x8 b2 = *(const bf16x8*)(bp + 1024);
    bf16x8 b3 = *(const bf16x8*)(bp + 1536);

    acc0 = __builtin_amdgcn_mfma_f32_16x16x32_bf16(afrag, b0, acc0, 0, 0, 0);
    acc1 = __builtin_amdgcn_mfma_f32_16x16x32_bf16(afrag, b1, acc1, 0, 0, 0);
    acc2 = __builtin_amdgcn_mfma_f32_16x16x32_bf16(afrag, b2, acc2, 0, 0, 0);
    acc3 = __builtin_amdgcn_mfma_f32_16x16x32_bf16(afrag, b3, acc3, 0, 0, 0);
  }

  // full-row denominator (wave w owns row w's entire j-range)
#pragma unroll
  for (int off = 1; off <= 32; off <<= 1) den += __shfl_xor(den, off, 64);

  __syncthreads();   // all pw reads done before aliasing lds as num

  // C layout: col = lane&15 (n), row = kgrp*4 + reg (m)
#pragma unroll
  for (int r = 0; r < 4; ++r) {
    lds_num[wv][kgrp * 4 + r][0 * 16 + r15] = acc0[r];
    lds_num[wv][kgrp * 4 + r][1 * 16 + r15] = acc1[r];
    lds_num[wv][kgrp * 4 + r][2 * 16 + r15] = acc2[r];
    lds_num[wv][kgrp * 4 + r][3 * 16 + r15] = acc3[r];
  }
  if (lane == 0) lds_den[wv] = den;
  __syncthreads();

  // combine 16 k-partials, divide, elu, store: one element per thread
  {
    const int orow = tid >> 6;
    const int ocol = tid & 63;
    float s = 0.0f;
#pragma unroll
    for (int v = 0; v < 16; ++v) s += lds_num[v][orow][ocol];
    float vv = s / lds_den[orow];
    out[(size_t)(rg * 16 + orow) * FOUT + ocol] = (vv > 0.0f) ? vv : (__expf(vv) - 1.0f);
  }
}

extern "C" void kernel_launch(void* const* d_in, const int* in_sizes, int n_in,
                              void* d_out, int out_size, void* d_ws, size_t ws_size,
                              hipStream_t stream) {
  const float* x = (const float*)d_in[0];
  const int* adj = (const int*)d_in[1];
  const float* W = (const float*)d_in[2];
  const float* a = (const float*)d_in[3];
  float* out = (float*)d_out;

  char* ws = (char*)d_ws;
  unsigned short* bpack = (unsigned short*)ws;                 // 64*8192*2 = 1 MB
  float* f1 = (float*)(ws + (size_t)FOUT * NN * 2);            // 32 KB
  float* f2 = f1 + NN;                                         // 32 KB

  hipLaunchKernelGGL(prep_kernel, dim3(256), dim3(256), 0, stream, x, W, a, bpack, f1, f2);
  hipLaunchKernelGGL(attn_kernel, dim3(512), dim3(1024), 0, stream, adj, bpack, f1, f2, out);
}

// Round 4
// 127.014 us; speedup vs baseline: 1.2502x; 1.0055x over previous
//
#include <hip/hip_runtime.h>
#include <stdint.h>

#define NN 8192
#define FIN 512
#define FOUT 64
#define ALPHA 0.2f
#define TJ 512
#define NT (NN / TJ)   // 16 tiles

typedef float f32x4 __attribute__((ext_vector_type(4)));
typedef int   i32x4 __attribute__((ext_vector_type(4)));
typedef short bf16x8 __attribute__((ext_vector_type(8)));

__device__ __forceinline__ unsigned short f2bf(float f) {
  union { float f; unsigned u; } v; v.f = f;
  unsigned r = (v.u + 0x7fffu + ((v.u >> 16) & 1u)) >> 16;
  return (unsigned short)r;
}

// ---------------- Phase 0: adj (int32) -> bitmask, pure barrier-free stream ----------------
// Wave wid handles 2048 consecutive ints: lane reads 8 ints (2 x i32x4), packs 1 byte, x4.
__device__ __forceinline__ unsigned packbits(i32x4 a, i32x4 b) {
  unsigned r = 0;
#pragma unroll
  for (int e = 0; e < 4; ++e) r |= (a[e] > 0 ? 1u : 0u) << e;
#pragma unroll
  for (int e = 0; e < 4; ++e) r |= (b[e] > 0 ? 1u : 0u) << (4 + e);
  return r;
}

__global__ __launch_bounds__(256) void compact_kernel(
    const int* __restrict__ adj, unsigned char* __restrict__ bits) {
  const int lane = threadIdx.x & 63;
  const int wid = blockIdx.x * 4 + (threadIdx.x >> 6);   // 0..32767
  const int* p0 = adj + (size_t)wid * 2048 + lane * 8;

  i32x4 va0 = *(const i32x4*)(p0);
  i32x4 vb0 = *(const i32x4*)(p0 + 4);
  i32x4 va1 = *(const i32x4*)(p0 + 512);
  i32x4 vb1 = *(const i32x4*)(p0 + 516);
  i32x4 va2 = *(const i32x4*)(p0 + 1024);
  i32x4 vb2 = *(const i32x4*)(p0 + 1028);
  i32x4 va3 = *(const i32x4*)(p0 + 1536);
  i32x4 vb3 = *(const i32x4*)(p0 + 1540);

  unsigned char* ob = bits + (size_t)wid * 256 + lane;
  ob[0]   = (unsigned char)packbits(va0, vb0);
  ob[64]  = (unsigned char)packbits(va1, vb1);
  ob[128] = (unsigned char)packbits(va2, vb2);
  ob[192] = (unsigned char)packbits(va3, vb3);
}

// ---------------- Phase 1: h = x@W (fp32), f1 = h@a1, f2 = h@a2, bpack = B-fragment layout ---
// bpack[jb][cb][lane=kgrp*16+r15][e] shorts: h[j = jb*32 + kgrp*8 + e][c = cb*16 + r15]
__global__ __launch_bounds__(256) void prep_kernel(
    const float* __restrict__ x, const float* __restrict__ W,
    const float* __restrict__ a, unsigned short* __restrict__ bpack,
    float* __restrict__ f1, float* __restrict__ f2) {
  const int lane = threadIdx.x & 63;
  const int g = blockIdx.x * 4 + (threadIdx.x >> 6);  // wave id 0..1023
  const int i0 = g * 8;

  float acc[8];
#pragma unroll
  for (int r = 0; r < 8; ++r) acc[r] = 0.0f;

  for (int k = 0; k < FIN; k += 4) {
    float w0 = W[(k + 0) * FOUT + lane];
    float w1 = W[(k + 1) * FOUT + lane];
    float w2 = W[(k + 2) * FOUT + lane];
    float w3 = W[(k + 3) * FOUT + lane];
#pragma unroll
    for (int r = 0; r < 8; ++r) {
      f32x4 xv = *(const f32x4*)(x + (size_t)(i0 + r) * FIN + k);
      acc[r] = fmaf(xv[0], w0, acc[r]);
      acc[r] = fmaf(xv[1], w1, acc[r]);
      acc[r] = fmaf(xv[2], w2, acc[r]);
      acc[r] = fmaf(xv[3], w3, acc[r]);
    }
  }

  const float a1c = a[lane];
  const float a2c = a[FOUT + lane];
#pragma unroll
  for (int r = 0; r < 8; ++r) {
    float p1 = acc[r] * a1c;
    float p2 = acc[r] * a2c;
#pragma unroll
    for (int off = 32; off >= 1; off >>= 1) {
      p1 += __shfl_xor(p1, off, 64);
      p2 += __shfl_xor(p2, off, 64);
    }
    if (lane == 0) { f1[i0 + r] = p1; f2[i0 + r] = p2; }
  }

  unsigned short hs[8];
#pragma unroll
  for (int r = 0; r < 8; ++r) hs[r] = f2bf(acc[r]);
  const int jb = i0 >> 5;
  const int kg = (i0 >> 3) & 3;
  const int cb = lane >> 4;
  const int rr = lane & 15;
  *(uint4*)(bpack + ((size_t)jb * 2048 + cb * 512 + kg * 128 + rr * 8)) = *(uint4*)hs;
}

// ---------------- Phase 2: fused GAT attention from bitmask (no HBM in the barrier loop) ----
// Block = 16 rows, 16 waves. Wave wv owns row wv (weights) and k-slice wv (MFMA).
__global__ __launch_bounds__(1024, 4) void attn_kernel(
    const unsigned char* __restrict__ bits, const unsigned short* __restrict__ bpack,
    const float* __restrict__ f1, const float* __restrict__ f2,
    float* __restrict__ out) {
  __shared__ __align__(16) char lds[16 * 16 * 64 * 4];  // 64 KB: pw dbuf (2x16KB) / num union
  __shared__ float lds_den[16];

  char* pwb0 = lds;            // pw buffer 0: [16 rows][512] bf16, swizzled
  char* pwb1 = lds + 16384;    // pw buffer 1
  float (*lds_num)[16][64] = (float (*)[16][64])lds;

  const int tid = threadIdx.x;
  const int lane = tid & 63;
  const int wv = tid >> 6;     // 0..15 : row owner AND k-slice owner
  const int rg = blockIdx.x;   // 0..511
  const int r15 = lane & 15;
  const int kgrp = lane >> 4;

  const int row_w = rg * 16 + wv;
  const float f1w = f1[row_w];
  const unsigned char* bitsrow = bits + (size_t)row_w * (NN / 8);

  // LDS addresses (bytes); lane owns j = lane*8..+7 of the tile on the write side
  int ard = r15 * 1024 + wv * 64 + kgrp * 16;
  ard ^= (r15 & 7) << 4;                       // swizzled A-frag read
  int awr = wv * 1024 + lane * 16;
  awr ^= (wv & 7) << 4;                        // swizzled weight write (16B per lane)

  f32x4 acc0 = {0.f, 0.f, 0.f, 0.f};
  f32x4 acc1 = acc0, acc2 = acc0, acc3 = acc0;
  float den = 0.0f;

  // prefetch tile 0 mask byte + f2
  unsigned bcur = bitsrow[lane];
  f32x4 fA = *(const f32x4*)(f2 + lane * 8);
  f32x4 fB = *(const f32x4*)(f2 + lane * 8 + 4);

  for (int t = 0; t < NT; ++t) {
    // issue this iter's bpack loads early (L2, covered by weight VALU below)
    const unsigned short* bp = bpack + ((size_t)(t * 16 + wv) * 2048 + lane * 8);
    bf16x8 b0 = *(const bf16x8*)(bp);
    bf16x8 b1 = *(const bf16x8*)(bp + 512);
    bf16x8 b2 = *(const bf16x8*)(bp + 1024);
    bf16x8 b3 = *(const bf16x8*)(bp + 1536);

    // issue next iter's mask/f2 loads (L1/L2)
    const int tn = (t + 1) & (NT - 1);
    unsigned bnxt = bitsrow[tn * 64 + lane];
    f32x4 nfA = *(const f32x4*)(f2 + tn * TJ + lane * 8);
    f32x4 nfB = *(const f32x4*)(f2 + tn * TJ + lane * 8 + 4);

    // weights for row wv, j = t*512 + lane*8 .. +7
    unsigned short ws8[8];
    float dsum = 0.0f;
#pragma unroll
    for (int e = 0; e < 4; ++e) {
      float s = f1w + fA[e];
      float l = fmaxf(s, ALPHA * s);
      float ev = __expf(l);
      float w_ = ((bcur >> e) & 1u) ? ev : 0.0f;
      dsum += w_;
      ws8[e] = f2bf(w_);
    }
#pragma unroll
    for (int e = 0; e < 4; ++e) {
      float s = f1w + fB[e];
      float l = fmaxf(s, ALPHA * s);
      float ev = __expf(l);
      float w_ = ((bcur >> (4 + e)) & 1u) ? ev : 0.0f;
      dsum += w_;
      ws8[4 + e] = f2bf(w_);
    }
    den += dsum;

    char* pwb = (t & 1) ? pwb1 : pwb0;
    *(uint4*)(pwb + awr) = *(uint4*)ws8;

    __syncthreads();   // pw visible; bpack/bits/f2 loads issued ~600cy ago -> drain is free

    // MFMA phase: this wave handles k-slice [t*512 + wv*32, +32)
    bf16x8 afrag = *(bf16x8*)(pwb + ard);
    acc0 = __builtin_amdgcn_mfma_f32_16x16x32_bf16(afrag, b0, acc0, 0, 0, 0);
    acc1 = __builtin_amdgcn_mfma_f32_16x16x32_bf16(afrag, b1, acc1, 0, 0, 0);
    acc2 = __builtin_amdgcn_mfma_f32_16x16x32_bf16(afrag, b2, acc2, 0, 0, 0);
    acc3 = __builtin_amdgcn_mfma_f32_16x16x32_bf16(afrag, b3, acc3, 0, 0, 0);

    bcur = bnxt; fA = nfA; fB = nfB;
  }

  // full-row denominator (wave wv owns row wv's entire j-range)
#pragma unroll
  for (int off = 1; off <= 32; off <<= 1) den += __shfl_xor(den, off, 64);

  __syncthreads();   // all pw reads done before aliasing lds as num

  // C layout: col = lane&15 (n), row = kgrp*4 + reg (m)
#pragma unroll
  for (int r = 0; r < 4; ++r) {
    lds_num[wv][kgrp * 4 + r][0 * 16 + r15] = acc0[r];
    lds_num[wv][kgrp * 4 + r][1 * 16 + r15] = acc1[r];
    lds_num[wv][kgrp * 4 + r][2 * 16 + r15] = acc2[r];
    lds_num[wv][kgrp * 4 + r][3 * 16 + r15] = acc3[r];
  }
  if (lane == 0) lds_den[wv] = den;
  __syncthreads();

  // combine 16 k-partials, divide, elu, store: one element per thread
  {
    const int orow = tid >> 6;
    const int ocol = tid & 63;
    float s = 0.0f;
#pragma unroll
    for (int v = 0; v < 16; ++v) s += lds_num[v][orow][ocol];
    float vv = s / lds_den[orow];
    out[(size_t)(rg * 16 + orow) * FOUT + ocol] = (vv > 0.0f) ? vv : (__expf(vv) - 1.0f);
  }
}

extern "C" void kernel_launch(void* const* d_in, const int* in_sizes, int n_in,
                              void* d_out, int out_size, void* d_ws, size_t ws_size,
                              hipStream_t stream) {
  const float* x = (const float*)d_in[0];
  const int* adj = (const int*)d_in[1];
  const float* W = (const float*)d_in[2];
  const float* a = (const float*)d_in[3];
  float* out = (float*)d_out;

  char* ws = (char*)d_ws;
  unsigned short* bpack = (unsigned short*)ws;                 // 1 MB
  float* f1 = (float*)(ws + (size_t)FOUT * NN * 2);            // 32 KB
  float* f2 = f1 + NN;                                         // 32 KB
  unsigned char* bits = (unsigned char*)(ws + (2u << 20));     // 8 MB at offset 2MB

  hipLaunchKernelGGL(compact_kernel, dim3(8192), dim3(256), 0, stream, adj, bits);
  hipLaunchKernelGGL(prep_kernel, dim3(256), dim3(256), 0, stream, x, W, a, bpack, f1, f2);
  hipLaunchKernelGGL(attn_kernel, dim3(512), dim3(1024), 0, stream, bits, bpack, f1, f2, out);
}